// Round 6
// baseline (292.363 us; speedup 1.0000x reference)
//
#include <hip/hip_runtime.h>
#include <hip/hip_bf16.h>
#include <math.h>

typedef unsigned int  u32;
typedef unsigned short u16;
typedef unsigned long long u64;

using bf16x8  = __attribute__((ext_vector_type(8))) __bf16;
using float4v = __attribute__((ext_vector_type(4))) float;

#define MFMA16(a,b,c) __builtin_amdgcn_mfma_f32_16x16x32_bf16(a,b,c,0,0,0)

// ---- fast-path workspace layout (bytes) — total 338 KB ----
#define W1P_OFF   0u          // 12288 u16
#define W2P_OFF   24576u      // 4096 u16
#define GWP_OFF   40960u      // 1024 u16 (gate padded to m=16)
#define E1P_OFF   43008u      // 65536 u16 (4 experts x 16384)
#define E2P_OFF   174080u     // 65536 u16 (4 experts x 16384)
#define ZF_OFF    305152u     // 8192 f32
#define CNTF_OFF  337920u     // 4 u32
#define PSUMF_OFF 337984u     // 4 f32
#define FAST_WS_BYTES 338048u

// fallback (R3) layout
#define Z_OFF    0u
#define CNT_OFF  32768u
#define PSUM_OFF 32832u

__device__ inline u16 f2bf(float f){
  union { float f; u32 u; } v; v.f = f;
  u32 r = v.u + 0x7fffu + ((v.u >> 16) & 1u);   // RNE
  return (u16)(r >> 16);
}
// packed RNE pair convert (v_cvt_pk_bf16_f32 on gfx950 via HIP header)
__device__ inline u32 pk2(float a, float b){
  union { __hip_bfloat162 h2; u32 u; } v;
  v.h2 = __float22bfloat162_rn(make_float2(a, b));
  return v.u;
}

// GELU via A&S 7.1.26 erf (|err|<=1.5e-7, branchless). gelu(x)=0.5x(1+erf(x/sqrt2)).
__device__ inline float geluf(float x){
  float u = fabsf(x) * 0.70710678118654752f;
  float t = 1.0f / (1.0f + 0.3275911f * u);
  float poly = t*(0.254829592f + t*(-0.284496736f +
               t*(1.421413741f + t*(-1.453152027f + t*1.061405429f))));
  float er = 1.0f - poly * __expf(-u*u);
  return 0.5f * x * (1.0f + copysignf(er, x));
}

// ================= k0: pack weights to MFMA A-frag layout (coalesced reads) ===========
// A-frag: lane l holds m=l&15, k=kc*32+(l>>4)*8+j ; packed idx = ((kc*MT+mt)*64+lane)*8+j
__global__ __launch_bounds__(256) void k0_pack(
    const float* __restrict__ w1, const float* __restrict__ w2, const float* __restrict__ gw,
    const float* __restrict__ e1, const float* __restrict__ e2,
    u16* w1p, u16* w2p, u16* gwp, u16* e1p, u16* e2p,
    float* z, u32* cnt, float* psum)
{
  int p = blockIdx.x*256 + threadIdx.x;
  if (p < 12288){                         // w1 [192][64] -> KC=6,MT=4
    int k = p >> 6, m = p & 63;
    int kc = k>>5, q = (k>>3)&3, j = k&7, mt = m>>4, col = m&15;
    w1p[((kc*4+mt)*64 + q*16+col)*8 + j] = f2bf(w1[p]); return;
  }
  p -= 12288;
  if (p < 4096){                          // w2 [64][64] -> KC=2,MT=4
    int k = p >> 6, m = p & 63;
    int kc = k>>5, q = (k>>3)&3, j = k&7, mt = m>>4, col = m&15;
    w2p[((kc*4+mt)*64 + q*16+col)*8 + j] = f2bf(w2[p]); return;
  }
  p -= 4096;
  if (p < 1024){                          // gw [64][4] -> KC=2, M=4 zero-pad to 16 (dest-indexed)
    int j = p & 7, lane = (p>>3) & 63;
    int col = lane & 15, q = lane >> 4, kc = p >> 9;
    int k = kc*32 + q*8 + j;
    gwp[p] = (col < 4) ? f2bf(gw[k*4 + col]) : (u16)0; return;
  }
  p -= 1024;
  if (p < 65536){                         // e1 [e][64][256] -> per e: KC=2,MT=16
    int e = p >> 14, r = p & 16383;
    int k = r >> 8, m = r & 255;
    int kc = k>>5, q = (k>>3)&3, j = k&7, mt = m>>4, col = m&15;
    e1p[e*16384 + ((kc*16+mt)*64 + q*16+col)*8 + j] = f2bf(e1[p]); return;
  }
  p -= 65536;
  if (p < 65536){                         // e2 [e][256][64] -> per e: KC=8,MT=4
    int e = p >> 14, r = p & 16383;
    int k = r >> 6, m = r & 63;
    int kc = k>>5, q = (k>>3)&3, j = k&7, mt = m>>4, col = m&15;
    e2p[e*16384 + ((kc*4+mt)*64 + q*16+col)*8 + j] = f2bf(e2[p]); return;
  }
  p -= 65536;
  if (p < 8192){ z[p] = 0.f; return; }
  p -= 8192;
  if (p < 4){ cnt[p] = 0u; return; }
  p -= 4;
  if (p < 4){ psum[p] = 0.f; return; }
}

// ================= kMain: fused pipeline, low-LDS / low-barrier version ===============
__global__ __launch_bounds__(256) void kMain(
    const float* __restrict__ x,
    const float* __restrict__ b1, const float* __restrict__ b2, const float* __restrict__ gb,
    const u16* __restrict__ w1p, const u16* __restrict__ w2p, const u16* __restrict__ gwp,
    const u16* __restrict__ e1p, const u16* __restrict__ e2p,
    const float* __restrict__ eb1, const float* __restrict__ eb2,
    float* __restrict__ z, u32* __restrict__ cnt, float* __restrict__ psum)
{
  __shared__ char h1l[8192];      // 64 rows x 128B (wave-private rows)
  __shared__ char hl[8192];       // 64 rows x 128B (cross-wave read after barrier)
  __shared__ char hidp[8192];     // 4 waves x 2KB: wave-private hid tile, then partials
  __shared__ int   be_s[64];
  __shared__ float gv_s[64];
  __shared__ int   sperm[64];
  __shared__ int   se_s[64];
  __shared__ float sg_s[64];
  __shared__ float lgp[4];
  __shared__ u32   lgc[4];

  const int tid  = threadIdx.x;
  const int tok0 = blockIdx.x * 64;
  if (tid < 4){ lgp[tid] = 0.f; lgc[tid] = 0u; }

  const int lane = tid & 63, wave = tid >> 6;
  const int col  = lane & 15, quad = lane >> 4;
  const int t    = wave*16 + col;          // own token (MFMA n-col)

  // ---- GEMM1 B-frags straight from global (wave-private; no LDS staging) ----
  bf16x8 bx[6];
  {
    const float* xrow = x + (size_t)(tok0 + t)*192 + quad*8;
    for (int kc = 0; kc < 6; ++kc){
      float4 f0 = *(const float4*)(xrow + kc*32);
      float4 f1 = *(const float4*)(xrow + kc*32 + 4);
      uint4 v;
      v.x = pk2(f0.x, f0.y); v.y = pk2(f0.z, f0.w);
      v.z = pk2(f1.x, f1.y); v.w = pk2(f1.z, f1.w);
      union { uint4 u; bf16x8 h; } cv; cv.u = v;
      bx[kc] = cv.h;
    }
  }

  // ---- GEMM1: h1T = gelu(W1^T x + b1) -> h1l (own rows; same-wave ds order, no barrier)
  for (int mt = 0; mt < 4; ++mt){
    float4v acc = {0.f,0.f,0.f,0.f};
    for (int kc = 0; kc < 6; ++kc){
      bf16x8 a = *(const bf16x8*)(w1p + ((kc*4 + mt)*64 + lane)*8);
      acc = MFMA16(a, bx[kc], acc);
    }
    int j0 = mt*16 + quad*4;
    float4 bb = *(const float4*)(b1 + j0);
    uint2 w; w.x = pk2(geluf(acc[0]+bb.x), geluf(acc[1]+bb.y));
             w.y = pk2(geluf(acc[2]+bb.z), geluf(acc[3]+bb.w));
    *(uint2*)(h1l + t*128 + (((2*mt + (quad>>1)) ^ (t & 7))*16) + (quad & 1)*8) = w;
  }

  // ---- GEMM2: hT = W2^T h1 + b2 -> hl (own rows, no barrier) ----
  {
    bf16x8 bh1[2];
    for (int kc = 0; kc < 2; ++kc)
      bh1[kc] = *(const bf16x8*)(h1l + t*128 + (((4*kc + quad) ^ (t & 7))*16));
    for (int mt = 0; mt < 4; ++mt){
      float4v acc = {0.f,0.f,0.f,0.f};
      for (int kc = 0; kc < 2; ++kc){
        bf16x8 a = *(const bf16x8*)(w2p + ((kc*4 + mt)*64 + lane)*8);
        acc = MFMA16(a, bh1[kc], acc);
      }
      int j0 = mt*16 + quad*4;
      float4 bb = *(const float4*)(b2 + j0);
      uint2 w; w.x = pk2(acc[0]+bb.x, acc[1]+bb.y);
               w.y = pk2(acc[2]+bb.z, acc[3]+bb.w);
      *(uint2*)(hl + t*128 + (((2*mt + (quad>>1)) ^ (t & 7))*16) + (quad & 1)*8) = w;
    }
  }

  // ---- gate (reads own hl row, no barrier): softmax/top-1 by quad-0 lanes ----
  {
    bf16x8 bh[2];
    for (int kc = 0; kc < 2; ++kc)
      bh[kc] = *(const bf16x8*)(hl + t*128 + (((4*kc + quad) ^ (t & 7))*16));
    float4v ag = {0.f,0.f,0.f,0.f};
    for (int kc = 0; kc < 2; ++kc){
      bf16x8 a = *(const bf16x8*)(gwp + (kc*64 + lane)*8);
      ag = MFMA16(a, bh[kc], ag);
    }
    if (quad == 0){
      float l0 = ag[0]+gb[0], l1 = ag[1]+gb[1], l2 = ag[2]+gb[2], l3 = ag[3]+gb[3];
      float mx = fmaxf(fmaxf(l0,l1), fmaxf(l2,l3));
      float x0 = __expf(l0-mx), x1 = __expf(l1-mx), x2 = __expf(l2-mx), x3 = __expf(l3-mx);
      float inv = 1.f/(x0+x1+x2+x3);
      float p0 = x0*inv, p1 = x1*inv, p2 = x2*inv, p3 = x3*inv;
      int be = 0; float bv = l0;
      if (l1 > bv){ bv = l1; be = 1; }
      if (l2 > bv){ bv = l2; be = 2; }
      if (l3 > bv){ bv = l3; be = 3; }
      be_s[t] = be;
      gv_s[t] = (be==0) ? p0 : (be==1) ? p1 : (be==2) ? p2 : p3;
      atomicAdd(&lgp[0], p0); atomicAdd(&lgp[1], p1);
      atomicAdd(&lgp[2], p2); atomicAdd(&lgp[3], p3);
      atomicAdd(&lgc[be], 1u);
    }
  }
  __syncthreads();                         // barrier 1: hl + routing visible block-wide

  // ---- wave 0: stable sort of 64 tokens by expert via ballot ranks ----
  if (tid < 64){
    int e = be_s[tid];
    u64 m0 = __ballot(e==0), m1 = __ballot(e==1), m2 = __ballot(e==2), m3 = __ballot(e==3);
    int c0 = __popcll(m0), c1 = __popcll(m1), c2 = __popcll(m2);
    int base = (e==0) ? 0 : (e==1) ? c0 : (e==2) ? c0+c1 : c0+c1+c2;
    u64 me = (e==0) ? m0 : (e==1) ? m1 : (e==2) ? m2 : m3;
    int pos = base + __popcll(me & ((1ull<<tid)-1ull));
    sperm[pos] = tid; se_s[pos] = e; sg_s[pos] = gv_s[tid];
  }
  __syncthreads();                         // barrier 2

  // ---- per-wave expert loop on its sorted 16-token slice (quarter-pass hid) ----
  const int slice = wave*16;
  const int tt    = sperm[slice + col];
  const int myE   = se_s[slice + col];
  const float myG = sg_s[slice + col];
  const int e_lo  = se_s[slice], e_hi = se_s[slice + 15];
  char* hb = hidp + wave*2048;             // wave-private 16 x 128B tile

  bf16x8 bhp[2];
  for (int kc = 0; kc < 2; ++kc)
    bhp[kc] = *(const bf16x8*)(hl + tt*128 + (((4*kc + quad) ^ (tt & 7))*16));

  float oacc[16];
  for (int i = 0; i < 16; ++i) oacc[i] = 0.f;

  for (int e = e_lo; e <= e_hi; ++e){
    const u16* W1 = e1p + e*16384;
    const u16* W2 = e2p + e*16384;
    float4v accE[4];
    for (int mt = 0; mt < 4; ++mt) accE[mt] = (float4v){0.f,0.f,0.f,0.f};
    for (int p = 0; p < 4; ++p){
      // L1 quarter: 64 hidden dims (mt = p*4+mt2), wave-private store
      for (int mt2 = 0; mt2 < 4; ++mt2){
        float4v acc = {0.f,0.f,0.f,0.f};
        for (int kc = 0; kc < 2; ++kc){
          bf16x8 a = *(const bf16x8*)(W1 + ((kc*16 + p*4 + mt2)*64 + lane)*8);
          acc = MFMA16(a, bhp[kc], acc);
        }
        int j0 = p*64 + mt2*16 + quad*4;
        float4 bb = *(const float4*)(eb1 + e*256 + j0);
        uint2 w; w.x = pk2(geluf(acc[0]+bb.x), geluf(acc[1]+bb.y));
                 w.y = pk2(geluf(acc[2]+bb.z), geluf(acc[3]+bb.w));
        *(uint2*)(hb + col*128 + (((2*mt2 + (quad>>1)) ^ (col & 7))*16) + (quad & 1)*8) = w;
      }
      // L2 partial-K: consume this quarter (same-wave ds order, no barrier)
      bf16x8 bhid0 = *(const bf16x8*)(hb + col*128 + (((0 + quad) ^ (col & 7))*16));
      bf16x8 bhid1 = *(const bf16x8*)(hb + col*128 + (((4 + quad) ^ (col & 7))*16));
      for (int mt = 0; mt < 4; ++mt){
        bf16x8 a0 = *(const bf16x8*)(W2 + (((p*2+0)*4 + mt)*64 + lane)*8);
        bf16x8 a1 = *(const bf16x8*)(W2 + (((p*2+1)*4 + mt)*64 + lane)*8);
        accE[mt] = MFMA16(a0, bhid0, accE[mt]);
        accE[mt] = MFMA16(a1, bhid1, accE[mt]);
      }
    }
    float wgt = (myE == e) ? myG : 0.f;
    for (int mt = 0; mt < 4; ++mt){
      float4 bb = *(const float4*)(eb2 + e*64 + mt*16 + quad*4);
      oacc[mt*4+0] += (accE[mt][0] + bb.x) * wgt;
      oacc[mt*4+1] += (accE[mt][1] + bb.y) * wgt;
      oacc[mt*4+2] += (accE[mt][2] + bb.z) * wgt;
      oacc[mt*4+3] += (accE[mt][3] + bb.w) * wgt;
    }
  }

  // ---- pooled reduction over 16 cols; partials into own (dead) hid tile ----
  for (int m = 1; m < 16; m <<= 1)
    for (int i = 0; i < 16; ++i)
      oacc[i] += __shfl_xor(oacc[i], m, 64);
  if (col == 0){
    float* pw = (float*)hb;
    for (int mt = 0; mt < 4; ++mt)
      for (int r = 0; r < 4; ++r)
        pw[mt*16 + quad*4 + r] = oacc[mt*4 + r];
  }
  __syncthreads();                         // barrier 3
  int b = blockIdx.x >> 4;                 // 16 blocks per batch row
  if (tid < 64){
    float s = ((const float*)(hidp))[tid]        + ((const float*)(hidp+2048))[tid]
            + ((const float*)(hidp+4096))[tid]   + ((const float*)(hidp+6144))[tid];
    atomicAdd(&z[b*64 + tid], s);
  }
  if (tid < 4){ atomicAdd(&cnt[tid], lgc[tid]); atomicAdd(&psum[tid], lgp[tid]); }
}

// ================= kFinal: mean pool + LayerNorm + classifier (+aux) ==================
__global__ __launch_bounds__(64) void kFinal(
    const float* __restrict__ z, const u32* __restrict__ cnt, const float* __restrict__ psum,
    const float* __restrict__ ln_g, const float* __restrict__ ln_b,
    const float* __restrict__ cw1, const float* __restrict__ cb1,
    const float* __restrict__ cw2, const float* __restrict__ cb2,
    float* __restrict__ out)
{
  __shared__ float z_l[64], zn_l[64], c1_l[64], red[2];
  int tid = threadIdx.x, b = blockIdx.x;
  z_l[tid] = z[b*64 + tid] * (1.0f/1024.0f);
  __syncthreads();
  if (tid == 0){
    float mu = 0.f; for (int i=0;i<64;++i) mu += z_l[i]; mu *= (1.f/64.f);
    float vv = 0.f; for (int i=0;i<64;++i){ float d=z_l[i]-mu; vv += d*d; } vv *= (1.f/64.f);
    red[0]=mu; red[1]=1.0f/sqrtf(vv+1e-5f);
  }
  __syncthreads();
  zn_l[tid] = (z_l[tid]-red[0])*red[1]*ln_g[tid] + ln_b[tid];
  __syncthreads();
  float a1 = cb1[tid];
  for (int k=0;k<64;++k) a1 += zn_l[k]*cw1[k*64+tid];
  c1_l[tid] = geluf(a1);
  __syncthreads();
  if (tid < 10){
    float y = cb2[tid];
    for (int k=0;k<64;++k) y += c1_l[k]*cw2[k*10+tid];
    out[b*10+tid] = y;
  }
  if (b == 0 && tid == 0){
    float aux = 0.f;
    for (int e=0;e<4;++e) aux += (float)cnt[e]*psum[e];
    out[1280] = 4.0f*aux/(131072.0f*131072.0f);
  }
}

// ================= fallback path (verified R3 fp32 kernels) ===========================
__global__ __launch_bounds__(256) void kInitF(float* z, u32* cnt, float* psum){
  int i = blockIdx.x*256 + threadIdx.x;
  if (i < 8192) z[i] = 0.f;
  if (i < 4){ cnt[i] = 0u; psum[i] = 0.f; }
}

__global__ __launch_bounds__(256) void kFusedF(
    const float* __restrict__ x,
    const float* __restrict__ w1, const float* __restrict__ b1,
    const float* __restrict__ w2, const float* __restrict__ b2,
    const float* __restrict__ gw, const float* __restrict__ gb,
    const float* __restrict__ e1, const float* __restrict__ eb1,
    const float* __restrict__ e2, const float* __restrict__ eb2,
    float* __restrict__ z, u32* __restrict__ cnt, float* __restrict__ psum)
{
  __shared__ float xs[4][192];
  __shared__ float h1s[4][64];
  __shared__ float hs[4][64];
  __shared__ float hid[4][256];
  __shared__ float lg[4][4];
  __shared__ int   be_s[4];
  __shared__ float gv_s[4];
  __shared__ float lgp[4];
  __shared__ u32   lgc[4];
  const int tid  = threadIdx.x;
  const int w    = tid >> 6, lane = tid & 63;
  const int tok  = blockIdx.x*4 + w;
  if (tid < 4){ lgp[tid] = 0.f; lgc[tid] = 0u; }
  for (int r = 0; r < 3; ++r)
    xs[w][lane + 64*r] = x[(size_t)tok*192 + lane + 64*r];
  __syncthreads();
  float a = b1[lane];
  for (int k = 0; k < 192; ++k) a += xs[w][k]*w1[k*64 + lane];
  h1s[w][lane] = geluf(a);
  __syncthreads();
  float h = b2[lane];
  for (int k = 0; k < 64; ++k) h += h1s[w][k]*w2[k*64 + lane];
  hs[w][lane] = h;
  __syncthreads();
  if (lane < 4){
    float l = gb[lane];
    for (int k = 0; k < 64; ++k) l += hs[w][k]*gw[k*4 + lane];
    lg[w][lane] = l;
  }
  __syncthreads();
  if (lane == 0){
    float l0=lg[w][0], l1=lg[w][1], l2=lg[w][2], l3=lg[w][3];
    float mx = fmaxf(fmaxf(l0,l1),fmaxf(l2,l3));
    float x0=expf(l0-mx), x1=expf(l1-mx), x2=expf(l2-mx), x3=expf(l3-mx);
    float inv = 1.f/(x0+x1+x2+x3);
    float p0=x0*inv, p1=x1*inv, p2=x2*inv, p3=x3*inv;
    int be=0; float bv=l0;
    if (l1>bv){bv=l1;be=1;}
    if (l2>bv){bv=l2;be=2;}
    if (l3>bv){bv=l3;be=3;}
    be_s[w]=be;
    gv_s[w]=(be==0)?p0:(be==1)?p1:(be==2)?p2:p3;
    atomicAdd(&lgp[0],p0); atomicAdd(&lgp[1],p1);
    atomicAdd(&lgp[2],p2); atomicAdd(&lgp[3],p3);
    atomicAdd(&lgc[be],1u);
  }
  __syncthreads();
  const int e    = be_s[w];
  const float gv = gv_s[w];
  const float* W1 = e1 + e*16384;
  const float* W2 = e2 + e*16384;
  for (int q = 0; q < 4; ++q){
    int j = q*64 + lane;
    float s = eb1[e*256 + j];
    for (int k = 0; k < 64; ++k) s += hs[w][k]*W1[k*256 + j];
    hid[w][j] = geluf(s);
  }
  __syncthreads();
  float o = eb2[e*64 + lane];
  for (int j = 0; j < 256; ++j) o += hid[w][j]*W2[j*64 + lane];
  int b = tok >> 10;
  atomicAdd(&z[b*64 + lane], o*gv);
  __syncthreads();
  if (tid < 4){ atomicAdd(&cnt[tid], lgc[tid]); atomicAdd(&psum[tid], lgp[tid]); }
}

// ======================================================================================
extern "C" void kernel_launch(void* const* d_in, const int* in_sizes, int n_in,
                              void* d_out, int out_size, void* d_ws, size_t ws_size,
                              hipStream_t stream)
{
  const float* x    = (const float*)d_in[0];
  const float* pw1  = (const float*)d_in[1];
  const float* pb1  = (const float*)d_in[2];
  const float* pw2  = (const float*)d_in[3];
  const float* pb2  = (const float*)d_in[4];
  const float* gw   = (const float*)d_in[5];
  const float* gb   = (const float*)d_in[6];
  const float* ew1  = (const float*)d_in[7];
  const float* eb1  = (const float*)d_in[8];
  const float* ew2  = (const float*)d_in[9];
  const float* eb2  = (const float*)d_in[10];
  const float* lng  = (const float*)d_in[11];
  const float* lnb  = (const float*)d_in[12];
  const float* cw1  = (const float*)d_in[13];
  const float* cb1  = (const float*)d_in[14];
  const float* cw2  = (const float*)d_in[15];
  const float* cb2  = (const float*)d_in[16];
  char* ws  = (char*)d_ws;
  float* out = (float*)d_out;

  if (ws_size >= FAST_WS_BYTES){
    u16*  w1p  = (u16*)(ws + W1P_OFF);
    u16*  w2p  = (u16*)(ws + W2P_OFF);
    u16*  gwp  = (u16*)(ws + GWP_OFF);
    u16*  e1p  = (u16*)(ws + E1P_OFF);
    u16*  e2p  = (u16*)(ws + E2P_OFF);
    float* z    = (float*)(ws + ZF_OFF);
    u32*  cnt  = (u32*)(ws + CNTF_OFF);
    float* psum = (float*)(ws + PSUMF_OFF);
    k0_pack<<<613, 256, 0, stream>>>(pw1, pw2, gw, ew1, ew2,
                                     w1p, w2p, gwp, e1p, e2p, z, cnt, psum);
    kMain <<<2048, 256, 0, stream>>>(x, pb1, pb2, gb, w1p, w2p, gwp, e1p, e2p,
                                     eb1, eb2, z, cnt, psum);
    kFinal<<<128, 64, 0, stream>>>(z, cnt, psum, lng, lnb, cw1, cb1, cw2, cb2, out);
  } else {
    float* z    = (float*)(ws + Z_OFF);
    u32*   cnt  = (u32*)(ws + CNT_OFF);
    float* psum = (float*)(ws + PSUM_OFF);
    kInitF <<<32,    256, 0, stream>>>(z, cnt, psum);
    kFusedF<<<32768, 256, 0, stream>>>(x, pw1, pb1, pw2, pb2, gw, gb,
                                       ew1, eb1, ew2, eb2, z, cnt, psum);
    kFinal <<<128,   64,  0, stream>>>(z, cnt, psum, lng, lnb, cw1, cb1, cw2, cb2, out);
  }
}

// Round 7
// 271.015 us; speedup vs baseline: 1.0788x; 1.0788x over previous
//
#include <hip/hip_runtime.h>
#include <hip/hip_bf16.h>
#include <math.h>

typedef unsigned int  u32;
typedef unsigned short u16;
typedef unsigned long long u64;

using bf16x8  = __attribute__((ext_vector_type(8))) __bf16;
using float4v = __attribute__((ext_vector_type(4))) float;

#define MFMA16(a,b,c) __builtin_amdgcn_mfma_f32_16x16x32_bf16(a,b,c,0,0,0)

// ---- fast-path workspace layout (bytes) — total 338 KB ----
#define W1P_OFF   0u          // 12288 u16
#define W2P_OFF   24576u      // 4096 u16
#define GWP_OFF   40960u      // 1024 u16 (gate padded to m=16)
#define E1P_OFF   43008u      // 65536 u16 (4 experts x 16384)
#define E2P_OFF   174080u     // 65536 u16 (4 experts x 16384)
#define ZF_OFF    305152u     // 8192 f32
#define CNTF_OFF  337920u     // 4 u32
#define PSUMF_OFF 337984u     // 4 f32
#define FAST_WS_BYTES 338048u

// fallback (R3) layout
#define Z_OFF    0u
#define CNT_OFF  32768u
#define PSUM_OFF 32832u

__device__ inline u16 f2bf(float f){
  union { float f; u32 u; } v; v.f = f;
  u32 r = v.u + 0x7fffu + ((v.u >> 16) & 1u);   // RNE
  return (u16)(r >> 16);
}
// packed RNE pair convert (v_cvt_pk_bf16_f32)
__device__ inline u32 pk2(float a, float b){
  union { __hip_bfloat162 h2; u32 u; } v;
  v.h2 = __float22bfloat162_rn(make_float2(a, b));
  return v.u;
}

// GELU via A&S 7.1.26 erf, branchless, raw v_rcp (|err|~1e-7 << bf16 ulp).
__device__ inline float geluf(float x){
  float u = fabsf(x) * 0.70710678118654752f;
  float t = __builtin_amdgcn_rcpf(1.0f + 0.3275911f * u);
  float poly = t*(0.254829592f + t*(-0.284496736f +
               t*(1.421413741f + t*(-1.453152027f + t*1.061405429f))));
  float er = 1.0f - poly * __expf(-u*u);
  return 0.5f * x * (1.0f + copysignf(er, x));
}

// ================= k0: pack weights to MFMA A-frag layout (coalesced reads) ===========
// A-frag: lane l holds m=l&15, k=kc*32+(l>>4)*8+j ; packed idx = ((kc*MT+mt)*64+lane)*8+j
__global__ __launch_bounds__(256) void k0_pack(
    const float* __restrict__ w1, const float* __restrict__ w2, const float* __restrict__ gw,
    const float* __restrict__ e1, const float* __restrict__ e2,
    u16* w1p, u16* w2p, u16* gwp, u16* e1p, u16* e2p,
    float* z, u32* cnt, float* psum)
{
  int p = blockIdx.x*256 + threadIdx.x;
  if (p < 12288){                         // w1 [192][64] -> KC=6,MT=4
    int k = p >> 6, m = p & 63;
    int kc = k>>5, q = (k>>3)&3, j = k&7, mt = m>>4, col = m&15;
    w1p[((kc*4+mt)*64 + q*16+col)*8 + j] = f2bf(w1[p]); return;
  }
  p -= 12288;
  if (p < 4096){                          // w2 [64][64] -> KC=2,MT=4
    int k = p >> 6, m = p & 63;
    int kc = k>>5, q = (k>>3)&3, j = k&7, mt = m>>4, col = m&15;
    w2p[((kc*4+mt)*64 + q*16+col)*8 + j] = f2bf(w2[p]); return;
  }
  p -= 4096;
  if (p < 1024){                          // gw [64][4] -> KC=2, M=4 zero-pad to 16 (dest-indexed)
    int j = p & 7, lane = (p>>3) & 63;
    int col = lane & 15, q = lane >> 4, kc = p >> 9;
    int k = kc*32 + q*8 + j;
    gwp[p] = (col < 4) ? f2bf(gw[k*4 + col]) : (u16)0; return;
  }
  p -= 1024;
  if (p < 65536){                         // e1 [e][64][256] -> per e: KC=2,MT=16
    int e = p >> 14, r = p & 16383;
    int k = r >> 8, m = r & 255;
    int kc = k>>5, q = (k>>3)&3, j = k&7, mt = m>>4, col = m&15;
    e1p[e*16384 + ((kc*16+mt)*64 + q*16+col)*8 + j] = f2bf(e1[p]); return;
  }
  p -= 65536;
  if (p < 65536){                         // e2 [e][256][64] -> per e: KC=8,MT=4
    int e = p >> 14, r = p & 16383;
    int k = r >> 6, m = r & 63;
    int kc = k>>5, q = (k>>3)&3, j = k&7, mt = m>>4, col = m&15;
    e2p[e*16384 + ((kc*4+mt)*64 + q*16+col)*8 + j] = f2bf(e2[p]); return;
  }
  p -= 65536;
  if (p < 8192){ z[p] = 0.f; return; }
  p -= 8192;
  if (p < 4){ cnt[p] = 0u; return; }
  p -= 4;
  if (p < 4){ psum[p] = 0.f; return; }
}

// ================= kMain: wave-autonomous front end, 3 barriers, padded strides =======
// LDS strides: stage rows 400B (25 chunks), h/hid rows 144B. Both give <=2-way bank
// aliasing (free, m136) without XOR-swizzle address math.
__global__ __launch_bounds__(256) void kMain(
    const float* __restrict__ x,
    const float* __restrict__ b1, const float* __restrict__ b2, const float* __restrict__ gb,
    const u16* __restrict__ w1p, const u16* __restrict__ w2p, const u16* __restrict__ gwp,
    const u16* __restrict__ e1p, const u16* __restrict__ e2p,
    const float* __restrict__ eb1, const float* __restrict__ eb2,
    float* __restrict__ z, u32* __restrict__ cnt, float* __restrict__ psum)
{
  __shared__ char wreg[25600];    // 4 waves x 6400B: x-stage -> h1 -> hid quarters -> partials
  __shared__ char hl[9216];       // 64 rows x 144B (published at barrier 1)
  __shared__ int   be_s[64];
  __shared__ float gv_s[64];
  __shared__ int   sperm[64];
  __shared__ int   se_s[64];
  __shared__ float sg_s[64];
  __shared__ float lgp[4];
  __shared__ u32   lgc[4];

  const int tid  = threadIdx.x;
  const int lane = tid & 63, wave = tid >> 6;
  const int col  = lane & 15, quad = lane >> 4;
  const int tok0 = blockIdx.x * 64;
  const int t    = wave*16 + col;          // own token slot in block
  if (tid < 4){ lgp[tid] = 0.f; lgc[tid] = 0u; }

  char* wr = wreg + wave*6400;

  // ---- stage own 16 tokens (contiguous 12KB of x) -> bf16 LDS, coalesced, no barrier
  const float* xw = x + (size_t)(tok0 + wave*16)*192;
  for (int it = 0; it < 6; ++it){
    int task = it*64 + lane;               // 384 tasks: 16 rows x 24 chunks
    int tr = task / 24, c = task % 24;
    float4 f0 = *(const float4*)(xw + tr*192 + c*8);
    float4 f1 = *(const float4*)(xw + tr*192 + c*8 + 4);
    uint4 v;
    v.x = pk2(f0.x,f0.y); v.y = pk2(f0.z,f0.w);
    v.z = pk2(f1.x,f1.y); v.w = pk2(f1.z,f1.w);
    *(uint4*)(wr + tr*400 + c*16) = v;
  }

  // ---- B-frags for GEMM1 (token = own col) ----
  bf16x8 bx[6];
  for (int kc = 0; kc < 6; ++kc)
    bx[kc] = *(const bf16x8*)(wr + col*400 + (4*kc+quad)*16);

  // ---- GEMM1: h1T = gelu(W1^T x + b1) -> wave-private h1 tile (reuses stage space) ----
  char* h1t = wr;                          // 16 rows x 144B
  for (int mt = 0; mt < 4; ++mt){
    float4v acc = {0.f,0.f,0.f,0.f};
    for (int kc = 0; kc < 6; ++kc){
      bf16x8 a = *(const bf16x8*)(w1p + ((kc*4 + mt)*64 + lane)*8);
      acc = MFMA16(a, bx[kc], acc);
    }
    int j0 = mt*16 + quad*4;
    float4 bb = *(const float4*)(b1 + j0);
    uint2 w; w.x = pk2(geluf(acc[0]+bb.x), geluf(acc[1]+bb.y));
             w.y = pk2(geluf(acc[2]+bb.z), geluf(acc[3]+bb.w));
    *(uint2*)(h1t + col*144 + mt*32 + quad*8) = w;
  }

  // ---- GEMM2: hT = W2^T h1 + b2 -> hl own rows ----
  {
    bf16x8 bh1[2];
    for (int kc = 0; kc < 2; ++kc)
      bh1[kc] = *(const bf16x8*)(h1t + col*144 + (4*kc+quad)*16);
    for (int mt = 0; mt < 4; ++mt){
      float4v acc = {0.f,0.f,0.f,0.f};
      for (int kc = 0; kc < 2; ++kc){
        bf16x8 a = *(const bf16x8*)(w2p + ((kc*4 + mt)*64 + lane)*8);
        acc = MFMA16(a, bh1[kc], acc);
      }
      int j0 = mt*16 + quad*4;
      float4 bb = *(const float4*)(b2 + j0);
      uint2 w; w.x = pk2(acc[0]+bb.x, acc[1]+bb.y);
               w.y = pk2(acc[2]+bb.z, acc[3]+bb.w);
      *(uint2*)(hl + t*144 + mt*32 + quad*8) = w;
    }
  }

  // ---- gate via MFMA on own hl row; routing by quad-0 lanes (atomics deferred) ----
  float p0=0.f,p1=0.f,p2=0.f,p3=0.f; int be=0;
  {
    bf16x8 bh[2];
    for (int kc = 0; kc < 2; ++kc)
      bh[kc] = *(const bf16x8*)(hl + t*144 + (4*kc+quad)*16);
    float4v ag = {0.f,0.f,0.f,0.f};
    for (int kc = 0; kc < 2; ++kc){
      bf16x8 a = *(const bf16x8*)(gwp + (kc*64 + lane)*8);
      ag = MFMA16(a, bh[kc], ag);
    }
    if (quad == 0){
      float l0 = ag[0]+gb[0], l1 = ag[1]+gb[1], l2 = ag[2]+gb[2], l3 = ag[3]+gb[3];
      float mx = fmaxf(fmaxf(l0,l1), fmaxf(l2,l3));
      float x0 = __expf(l0-mx), x1 = __expf(l1-mx), x2 = __expf(l2-mx), x3 = __expf(l3-mx);
      float inv = __builtin_amdgcn_rcpf(x0+x1+x2+x3);
      p0 = x0*inv; p1 = x1*inv; p2 = x2*inv; p3 = x3*inv;
      float bv = l0; be = 0;
      if (l1 > bv){ bv = l1; be = 1; }
      if (l2 > bv){ bv = l2; be = 2; }
      if (l3 > bv){ bv = l3; be = 3; }
      be_s[t] = be;
      gv_s[t] = (be==0) ? p0 : (be==1) ? p1 : (be==2) ? p2 : p3;
    }
  }
  __syncthreads();                         // barrier 1: hl + routing published
  if (quad == 0){                          // post-init-ordered stats atomics
    atomicAdd(&lgp[0], p0); atomicAdd(&lgp[1], p1);
    atomicAdd(&lgp[2], p2); atomicAdd(&lgp[3], p3);
    atomicAdd(&lgc[be], 1u);
  }

  // ---- wave 0: stable sort of 64 tokens by expert via ballot ranks ----
  if (tid < 64){
    int e = be_s[tid];
    u64 m0 = __ballot(e==0), m1 = __ballot(e==1), m2 = __ballot(e==2), m3 = __ballot(e==3);
    int c0 = __popcll(m0), c1 = __popcll(m1), c2 = __popcll(m2);
    int base = (e==0) ? 0 : (e==1) ? c0 : (e==2) ? c0+c1 : c0+c1+c2;
    u64 me = (e==0) ? m0 : (e==1) ? m1 : (e==2) ? m2 : m3;
    int pos = base + __popcll(me & ((1ull<<tid)-1ull));
    sperm[pos] = tid; se_s[pos] = e; sg_s[pos] = gv_s[tid];
  }
  __syncthreads();                         // barrier 2

  // ---- per-wave expert loop on sorted 16-token slice (quarter-pass hid, no barriers)
  const int slice = wave*16;
  const int tt    = sperm[slice + col];
  const int myE   = se_s[slice + col];
  const float myG = sg_s[slice + col];
  const int e_lo  = se_s[slice], e_hi = se_s[slice + 15];
  char* hbt = wr;                          // wave-private 16 x 144B hid quarter tile

  bf16x8 bhp[2];
  for (int kc = 0; kc < 2; ++kc)
    bhp[kc] = *(const bf16x8*)(hl + tt*144 + (4*kc+quad)*16);

  float oacc[16];
  for (int i = 0; i < 16; ++i) oacc[i] = 0.f;

  for (int e = e_lo; e <= e_hi; ++e){
    const u16* W1 = e1p + e*16384;
    const u16* W2 = e2p + e*16384;
    float4v accE[4];
    for (int mt = 0; mt < 4; ++mt) accE[mt] = (float4v){0.f,0.f,0.f,0.f};
    for (int p = 0; p < 4; ++p){
      for (int mt2 = 0; mt2 < 4; ++mt2){
        float4v acc = {0.f,0.f,0.f,0.f};
        for (int kc = 0; kc < 2; ++kc){
          bf16x8 a = *(const bf16x8*)(W1 + ((kc*16 + p*4 + mt2)*64 + lane)*8);
          acc = MFMA16(a, bhp[kc], acc);
        }
        int j0 = p*64 + mt2*16 + quad*4;
        float4 bb = *(const float4*)(eb1 + e*256 + j0);
        uint2 w; w.x = pk2(geluf(acc[0]+bb.x), geluf(acc[1]+bb.y));
                 w.y = pk2(geluf(acc[2]+bb.z), geluf(acc[3]+bb.w));
        *(uint2*)(hbt + col*144 + mt2*32 + quad*8) = w;
      }
      bf16x8 bq0 = *(const bf16x8*)(hbt + col*144 + quad*16);
      bf16x8 bq1 = *(const bf16x8*)(hbt + col*144 + (4+quad)*16);
      for (int mt = 0; mt < 4; ++mt){
        bf16x8 a0 = *(const bf16x8*)(W2 + (((p*2+0)*4 + mt)*64 + lane)*8);
        bf16x8 a1 = *(const bf16x8*)(W2 + (((p*2+1)*4 + mt)*64 + lane)*8);
        accE[mt] = MFMA16(a0, bq0, accE[mt]);
        accE[mt] = MFMA16(a1, bq1, accE[mt]);
      }
    }
    float wgt = (myE == e) ? myG : 0.f;
    for (int mt = 0; mt < 4; ++mt){
      float4 bb = *(const float4*)(eb2 + e*64 + mt*16 + quad*4);
      oacc[mt*4+0] += (accE[mt][0] + bb.x) * wgt;
      oacc[mt*4+1] += (accE[mt][1] + bb.y) * wgt;
      oacc[mt*4+2] += (accE[mt][2] + bb.z) * wgt;
      oacc[mt*4+3] += (accE[mt][3] + bb.w) * wgt;
    }
  }

  // ---- pooled reduction over 16 cols; partials into wave region ----
  for (int m = 1; m < 16; m <<= 1)
    for (int i = 0; i < 16; ++i)
      oacc[i] += __shfl_xor(oacc[i], m, 64);
  if (col == 0){
    float* pw = (float*)wr;
    for (int mt = 0; mt < 4; ++mt)
      for (int r = 0; r < 4; ++r)
        pw[mt*16 + quad*4 + r] = oacc[mt*4 + r];
  }
  __syncthreads();                         // barrier 3
  int b = blockIdx.x >> 4;                 // 16 blocks per batch row
  if (tid < 64){
    float s = *(const float*)(wreg + tid*4)         + *(const float*)(wreg + 6400 + tid*4)
            + *(const float*)(wreg + 12800 + tid*4) + *(const float*)(wreg + 19200 + tid*4);
    atomicAdd(&z[b*64 + tid], s);
  }
  if (tid < 4){ atomicAdd(&cnt[tid], lgc[tid]); atomicAdd(&psum[tid], lgp[tid]); }
}

// ================= kFinal: mean pool + LayerNorm + classifier (+aux) ==================
__global__ __launch_bounds__(64) void kFinal(
    const float* __restrict__ z, const u32* __restrict__ cnt, const float* __restrict__ psum,
    const float* __restrict__ ln_g, const float* __restrict__ ln_b,
    const float* __restrict__ cw1, const float* __restrict__ cb1,
    const float* __restrict__ cw2, const float* __restrict__ cb2,
    float* __restrict__ out)
{
  __shared__ float z_l[64], zn_l[64], c1_l[64], red[2];
  int tid = threadIdx.x, b = blockIdx.x;
  z_l[tid] = z[b*64 + tid] * (1.0f/1024.0f);
  __syncthreads();
  if (tid == 0){
    float mu = 0.f; for (int i=0;i<64;++i) mu += z_l[i]; mu *= (1.f/64.f);
    float vv = 0.f; for (int i=0;i<64;++i){ float d=z_l[i]-mu; vv += d*d; } vv *= (1.f/64.f);
    red[0]=mu; red[1]=1.0f/sqrtf(vv+1e-5f);
  }
  __syncthreads();
  zn_l[tid] = (z_l[tid]-red[0])*red[1]*ln_g[tid] + ln_b[tid];
  __syncthreads();
  float a1 = cb1[tid];
  for (int k=0;k<64;++k) a1 += zn_l[k]*cw1[k*64+tid];
  c1_l[tid] = geluf(a1);
  __syncthreads();
  if (tid < 10){
    float y = cb2[tid];
    for (int k=0;k<64;++k) y += c1_l[k]*cw2[k*10+tid];
    out[b*10+tid] = y;
  }
  if (b == 0 && tid == 0){
    float aux = 0.f;
    for (int e=0;e<4;++e) aux += (float)cnt[e]*psum[e];
    out[1280] = 4.0f*aux/(131072.0f*131072.0f);
  }
}

// ================= fallback path (verified R3 fp32 kernels) ===========================
__global__ __launch_bounds__(256) void kInitF(float* z, u32* cnt, float* psum){
  int i = blockIdx.x*256 + threadIdx.x;
  if (i < 8192) z[i] = 0.f;
  if (i < 4){ cnt[i] = 0u; psum[i] = 0.f; }
}

__global__ __launch_bounds__(256) void kFusedF(
    const float* __restrict__ x,
    const float* __restrict__ w1, const float* __restrict__ b1,
    const float* __restrict__ w2, const float* __restrict__ b2,
    const float* __restrict__ gw, const float* __restrict__ gb,
    const float* __restrict__ e1, const float* __restrict__ eb1,
    const float* __restrict__ e2, const float* __restrict__ eb2,
    float* __restrict__ z, u32* __restrict__ cnt, float* __restrict__ psum)
{
  __shared__ float xs[4][192];
  __shared__ float h1s[4][64];
  __shared__ float hs[4][64];
  __shared__ float hid[4][256];
  __shared__ float lg[4][4];
  __shared__ int   be_s[4];
  __shared__ float gv_s[4];
  __shared__ float lgp[4];
  __shared__ u32   lgc[4];
  const int tid  = threadIdx.x;
  const int w    = tid >> 6, lane = tid & 63;
  const int tok  = blockIdx.x*4 + w;
  if (tid < 4){ lgp[tid] = 0.f; lgc[tid] = 0u; }
  for (int r = 0; r < 3; ++r)
    xs[w][lane + 64*r] = x[(size_t)tok*192 + lane + 64*r];
  __syncthreads();
  float a = b1[lane];
  for (int k = 0; k < 192; ++k) a += xs[w][k]*w1[k*64 + lane];
  h1s[w][lane] = geluf(a);
  __syncthreads();
  float h = b2[lane];
  for (int k = 0; k < 64; ++k) h += h1s[w][k]*w2[k*64 + lane];
  hs[w][lane] = h;
  __syncthreads();
  if (lane < 4){
    float l = gb[lane];
    for (int k = 0; k < 64; ++k) l += hs[w][k]*gw[k*4 + lane];
    lg[w][lane] = l;
  }
  __syncthreads();
  if (lane == 0){
    float l0=lg[w][0], l1=lg[w][1], l2=lg[w][2], l3=lg[w][3];
    float mx = fmaxf(fmaxf(l0,l1),fmaxf(l2,l3));
    float x0=expf(l0-mx), x1=expf(l1-mx), x2=expf(l2-mx), x3=expf(l3-mx);
    float inv = 1.f/(x0+x1+x2+x3);
    float p0=x0*inv, p1=x1*inv, p2=x2*inv, p3=x3*inv;
    int be=0; float bv=l0;
    if (l1>bv){bv=l1;be=1;}
    if (l2>bv){bv=l2;be=2;}
    if (l3>bv){bv=l3;be=3;}
    be_s[w]=be;
    gv_s[w]=(be==0)?p0:(be==1)?p1:(be==2)?p2:p3;
    atomicAdd(&lgp[0],p0); atomicAdd(&lgp[1],p1);
    atomicAdd(&lgp[2],p2); atomicAdd(&lgp[3],p3);
    atomicAdd(&lgc[be],1u);
  }
  __syncthreads();
  const int e    = be_s[w];
  const float gv = gv_s[w];
  const float* W1 = e1 + e*16384;
  const float* W2 = e2 + e*16384;
  for (int q = 0; q < 4; ++q){
    int j = q*64 + lane;
    float s = eb1[e*256 + j];
    for (int k = 0; k < 64; ++k) s += hs[w][k]*W1[k*256 + j];
    hid[w][j] = geluf(s);
  }
  __syncthreads();
  float o = eb2[e*64 + lane];
  for (int j = 0; j < 256; ++j) o += hid[w][j]*W2[j*64 + lane];
  int b = tok >> 10;
  atomicAdd(&z[b*64 + lane], o*gv);
  __syncthreads();
  if (tid < 4){ atomicAdd(&cnt[tid], lgc[tid]); atomicAdd(&psum[tid], lgp[tid]); }
}

// ======================================================================================
extern "C" void kernel_launch(void* const* d_in, const int* in_sizes, int n_in,
                              void* d_out, int out_size, void* d_ws, size_t ws_size,
                              hipStream_t stream)
{
  const float* x    = (const float*)d_in[0];
  const float* pw1  = (const float*)d_in[1];
  const float* pb1  = (const float*)d_in[2];
  const float* pw2  = (const float*)d_in[3];
  const float* pb2  = (const float*)d_in[4];
  const float* gw   = (const float*)d_in[5];
  const float* gb   = (const float*)d_in[6];
  const float* ew1  = (const float*)d_in[7];
  const float* eb1  = (const float*)d_in[8];
  const float* ew2  = (const float*)d_in[9];
  const float* eb2  = (const float*)d_in[10];
  const float* lng  = (const float*)d_in[11];
  const float* lnb  = (const float*)d_in[12];
  const float* cw1  = (const float*)d_in[13];
  const float* cb1  = (const float*)d_in[14];
  const float* cw2  = (const float*)d_in[15];
  const float* cb2  = (const float*)d_in[16];
  char* ws  = (char*)d_ws;
  float* out = (float*)d_out;

  if (ws_size >= FAST_WS_BYTES){
    u16*  w1p  = (u16*)(ws + W1P_OFF);
    u16*  w2p  = (u16*)(ws + W2P_OFF);
    u16*  gwp  = (u16*)(ws + GWP_OFF);
    u16*  e1p  = (u16*)(ws + E1P_OFF);
    u16*  e2p  = (u16*)(ws + E2P_OFF);
    float* z    = (float*)(ws + ZF_OFF);
    u32*  cnt  = (u32*)(ws + CNTF_OFF);
    float* psum = (float*)(ws + PSUMF_OFF);
    k0_pack<<<613, 256, 0, stream>>>(pw1, pw2, gw, ew1, ew2,
                                     w1p, w2p, gwp, e1p, e2p, z, cnt, psum);
    kMain <<<2048, 256, 0, stream>>>(x, pb1, pb2, gb, w1p, w2p, gwp, e1p, e2p,
                                     eb1, eb2, z, cnt, psum);
    kFinal<<<128, 64, 0, stream>>>(z, cnt, psum, lng, lnb, cw1, cb1, cw2, cb2, out);
  } else {
    float* z    = (float*)(ws + Z_OFF);
    u32*   cnt  = (u32*)(ws + CNT_OFF);
    float* psum = (float*)(ws + PSUM_OFF);
    kInitF <<<32,    256, 0, stream>>>(z, cnt, psum);
    kFusedF<<<32768, 256, 0, stream>>>(x, pw1, pb1, pw2, pb2, gw, gb,
                                       ew1, eb1, ew2, eb2, z, cnt, psum);
    kFinal <<<128,   64,  0, stream>>>(z, cnt, psum, lng, lnb, cw1, cb1, cw2, cb2, out);
  }
}